// Round 3
// baseline (467.350 us; speedup 1.0000x reference)
//
#include <hip/hip_runtime.h>

#define D_FEAT 128

// --- 1. degree count: 4 edges per thread, 8 independent int atomics ---
__global__ void degree_kernel(const int* __restrict__ src, const int* __restrict__ dst,
                              int* __restrict__ deg_o, int* __restrict__ deg_i, int n_edges) {
    int t = blockIdx.x * blockDim.x + threadIdx.x;
    int e = t * 4;
    if (e + 3 < n_edges) {
        int4 s4 = *(const int4*)(src + e);
        int4 d4 = *(const int4*)(dst + e);
        atomicAdd(&deg_o[s4.x], 1);
        atomicAdd(&deg_o[s4.y], 1);
        atomicAdd(&deg_o[s4.z], 1);
        atomicAdd(&deg_o[s4.w], 1);
        atomicAdd(&deg_i[d4.x], 1);
        atomicAdd(&deg_i[d4.y], 1);
        atomicAdd(&deg_i[d4.z], 1);
        atomicAdd(&deg_i[d4.w], 1);
    } else {
        for (int i = e; i < n_edges; i++) {
            atomicAdd(&deg_o[src[i]], 1);
            atomicAdd(&deg_i[dst[i]], 1);
        }
    }
}

// --- scan step 1: per-1024-chunk block sums ---
__global__ void block_reduce_kernel(const int* __restrict__ deg, int* __restrict__ bsums, int n) {
    __shared__ int lds[256];
    int t = threadIdx.x;
    int base = blockIdx.x * 1024;
    int s = 0;
    for (int i = t; i < 1024; i += 256) {
        int idx = base + i;
        if (idx < n) s += deg[idx];
    }
    lds[t] = s;
    __syncthreads();
    for (int off = 128; off > 0; off >>= 1) {
        if (t < off) lds[t] += lds[t + off];
        __syncthreads();
    }
    if (t == 0) bsums[blockIdx.x] = lds[0];
}

// --- scan step 2: single-block exclusive scan of block sums (nb <= 256) ---
__global__ void scan_sums_kernel(int* __restrict__ bsums, int nb) {
    __shared__ int tmp[256];
    int t = threadIdx.x;
    int v = (t < nb) ? bsums[t] : 0;
    tmp[t] = v;
    __syncthreads();
    for (int off = 1; off < 256; off <<= 1) {
        int x = (t >= off) ? tmp[t - off] : 0;
        __syncthreads();
        tmp[t] += x;
        __syncthreads();
    }
    if (t < nb) bsums[t] = tmp[t] - v;  // exclusive
}

// --- scan step 3: final exclusive scan -> row_ptr + cursor; also deg -> rsqrt norms ---
__global__ void scan_final_kernel(int* __restrict__ deg_i, int* __restrict__ deg_o,
                                  const int* __restrict__ bsums,
                                  int* __restrict__ row_ptr, int* __restrict__ cursor,
                                  int n, int n_edges) {
    __shared__ int tmp[256];
    int t = threadIdx.x;
    int base = blockIdx.x * 1024 + t * 4;
    int v0 = 0, v1 = 0, v2 = 0, v3 = 0;
    if (base + 0 < n) v0 = deg_i[base + 0];
    if (base + 1 < n) v1 = deg_i[base + 1];
    if (base + 2 < n) v2 = deg_i[base + 2];
    if (base + 3 < n) v3 = deg_i[base + 3];
    int s = v0 + v1 + v2 + v3;
    tmp[t] = s;
    __syncthreads();
    for (int off = 1; off < 256; off <<= 1) {
        int x = (t >= off) ? tmp[t - off] : 0;
        __syncthreads();
        tmp[t] += x;
        __syncthreads();
    }
    int run = bsums[blockIdx.x] + tmp[t] - s;  // exclusive prefix at base
    int vv[4] = {v0, v1, v2, v3};
    for (int j = 0; j < 4; j++) {
        int idx = base + j;
        if (idx < n) {
            row_ptr[idx] = run;
            cursor[idx] = run;
            // in-place: deg (int) -> rsqrt(max(deg,1)) (float)
            int di = vv[j] < 1 ? 1 : vv[j];
            ((float*)deg_i)[idx] = rsqrtf((float)di);
            int dodeg = deg_o[idx];
            if (dodeg < 1) dodeg = 1;
            ((float*)deg_o)[idx] = rsqrtf((float)dodeg);
        }
        run += vv[j];
    }
    if (blockIdx.x == 0 && t == 0) row_ptr[n] = n_edges;
}

// --- 3. fill CSR: 4 edges per thread, 4 independent returning atomics ---
__global__ void fill_kernel(const int* __restrict__ src, const int* __restrict__ dst,
                            int* __restrict__ cursor, int* __restrict__ src_sorted, int n_edges) {
    int t = blockIdx.x * blockDim.x + threadIdx.x;
    int e = t * 4;
    if (e + 3 < n_edges) {
        int4 s4 = *(const int4*)(src + e);
        int4 d4 = *(const int4*)(dst + e);
        int p0 = atomicAdd(&cursor[d4.x], 1);
        int p1 = atomicAdd(&cursor[d4.y], 1);
        int p2 = atomicAdd(&cursor[d4.z], 1);
        int p3 = atomicAdd(&cursor[d4.w], 1);
        src_sorted[p0] = s4.x;
        src_sorted[p1] = s4.y;
        src_sorted[p2] = s4.z;
        src_sorted[p3] = s4.w;
    } else {
        for (int i = e; i < n_edges; i++) {
            int pos = atomicAdd(&cursor[dst[i]], 1);
            src_sorted[pos] = src[i];
        }
    }
}

// --- 4. pull-aggregate: 32 lanes per node; chunked edge loads + shfl broadcast for MLP ---
__global__ __launch_bounds__(256) void pull_kernel(
        const float* __restrict__ feat, const int* __restrict__ src_sorted,
        const int* __restrict__ row_ptr, const float* __restrict__ norm_l,
        const float* __restrict__ norm_r, float* __restrict__ out, int n_nodes) {
    long long gid = (long long)blockIdx.x * blockDim.x + threadIdx.x;
    int node = (int)(gid >> 5);
    int lane = (int)(gid & 31);
    if (node >= n_nodes) return;
    int beg = row_ptr[node];
    int end = row_ptr[node + 1];
    float4 acc = make_float4(0.f, 0.f, 0.f, 0.f);
    for (int k0 = beg; k0 < end; k0 += 32) {
        int kk = k0 + lane;
        int s = 0;
        float nl = 0.f;
        if (kk < end) {
            s = src_sorted[kk];
            nl = norm_l[s];
        }
        int cnt = end - k0;
        if (cnt > 32) cnt = 32;
        #pragma unroll 4
        for (int j = 0; j < cnt; j++) {
            int sj = __shfl(s, j, 32);
            float nj = __shfl(nl, j, 32);
            float4 v = ((const float4*)(feat + (size_t)sj * D_FEAT))[lane];
            acc.x += v.x * nj;
            acc.y += v.y * nj;
            acc.z += v.z * nj;
            acc.w += v.w * nj;
        }
    }
    float nr = norm_r[node];
    acc.x *= nr; acc.y *= nr; acc.z *= nr; acc.w *= nr;
    ((float4*)(out + (size_t)node * D_FEAT))[lane] = acc;
}

extern "C" void kernel_launch(void* const* d_in, const int* in_sizes, int n_in,
                              void* d_out, int out_size, void* d_ws, size_t ws_size,
                              hipStream_t stream) {
    const float* feat = (const float*)d_in[0];
    const int*   src  = (const int*)d_in[1];
    const int*   dst  = (const int*)d_in[2];
    float* out = (float*)d_out;

    const int n_nodes = in_sizes[0] / D_FEAT;   // 100000
    const int n_edges = in_sizes[1];            // 1600000

    const int NB = (n_nodes + 1023) / 1024;     // 98 scan blocks

    // ws layout (ints): deg_o/norm_l [n] | deg_i/norm_r [n] | row_ptr [n+1] |
    //                   cursor [n] | bsums [NB] | src_sorted [n_edges]
    int* deg_o      = (int*)d_ws;
    int* deg_i      = deg_o + n_nodes;
    int* row_ptr    = deg_i + n_nodes;
    int* cursor     = row_ptr + (n_nodes + 1);
    int* bsums      = cursor + n_nodes;
    int* src_sorted = bsums + NB;

    // zero only the degree counters (ws is poisoned before every timed call)
    hipMemsetAsync(d_ws, 0, (size_t)2 * n_nodes * sizeof(int), stream);

    // 1. degrees (4 edges/thread)
    {
        int nthreads = (n_edges + 3) / 4;
        degree_kernel<<<(nthreads + 255) / 256, 256, 0, stream>>>(src, dst, deg_o, deg_i, n_edges);
    }

    // 2. exclusive scan of deg_i -> row_ptr (+cursor), fused deg->norm conversion
    block_reduce_kernel<<<NB, 256, 0, stream>>>(deg_i, bsums, n_nodes);
    scan_sums_kernel<<<1, 256, 0, stream>>>(bsums, NB);
    scan_final_kernel<<<NB, 256, 0, stream>>>(deg_i, deg_o, bsums, row_ptr, cursor,
                                              n_nodes, n_edges);

    // 3. CSR fill (4 edges/thread)
    {
        int nthreads = (n_edges + 3) / 4;
        fill_kernel<<<(nthreads + 255) / 256, 256, 0, stream>>>(src, dst, cursor,
                                                                src_sorted, n_edges);
    }

    // 4. pull aggregation (no atomics), fused final scale
    {
        long long total = (long long)n_nodes * 32;
        int blocks = (int)((total + 255) / 256);
        pull_kernel<<<blocks, 256, 0, stream>>>(feat, src_sorted, row_ptr,
                                                (const float*)deg_o, (const float*)deg_i,
                                                out, n_nodes);
    }
}

// Round 4
// 413.794 us; speedup vs baseline: 1.1294x; 1.1294x over previous
//
#include <hip/hip_runtime.h>

#define D_FEAT 128
#define CHAINS 4

// --- 1. one-pass build: out-degree count + per-dst linked list ---
// head[d] = most recent edge with dst==d; nxt[e] = previous one (coalesced store).
__global__ void build_kernel(const int* __restrict__ src, const int* __restrict__ dst,
                             int* __restrict__ deg_o, int* __restrict__ head,
                             int* __restrict__ nxt, int n_edges) {
    int e = blockIdx.x * blockDim.x + threadIdx.x;
    if (e < n_edges) {
        atomicAdd(&deg_o[src[e]], 1);
        nxt[e] = atomicExch(&head[dst[e]], e);
    }
}

// --- 2. deg_o (int) -> rsqrt(max(deg,1)) (float), in place ---
__global__ void norm_kernel(int* __restrict__ deg, int n) {
    int i = blockIdx.x * blockDim.x + threadIdx.x;
    if (i < n) {
        int d = deg[i];
        if (d < 1) d = 1;
        ((float*)deg)[i] = rsqrtf((float)d);
    }
}

// --- 3. pull-aggregate: 32 lanes per node, 4 interleaved chains per group ---
// Chain values (e, s, nx) are group-uniform (all lanes load same address -> broadcast).
// 4 independent chains keep 4 nxt/src loads + 4 row gathers in flight, hiding the
// serial next-pointer latency. In-degree = chain length -> norm_r computed here.
__global__ __launch_bounds__(256) void pull_kernel(
        const float* __restrict__ feat, const int* __restrict__ src,
        const int* __restrict__ nxt, const int* __restrict__ head,
        const float* __restrict__ norm_l, float* __restrict__ out, int n_nodes) {
    long long gid = (long long)blockIdx.x * blockDim.x + threadIdx.x;
    int group = (int)(gid >> 5);
    int lane  = (int)(gid & 31);
    int nbase = group * CHAINS;
    if (nbase >= n_nodes) return;

    int    e[CHAINS];
    int    cnt[CHAINS];
    float4 acc[CHAINS];
    #pragma unroll
    for (int c = 0; c < CHAINS; c++) {
        int node = nbase + c;
        e[c] = (node < n_nodes) ? head[node] : -1;
        cnt[c] = 0;
        acc[c] = make_float4(0.f, 0.f, 0.f, 0.f);
    }

    while (e[0] >= 0 || e[1] >= 0 || e[2] >= 0 || e[3] >= 0) {
        int s[CHAINS], nx[CHAINS];
        // phase 1: issue all chain loads (independent, broadcast within group)
        #pragma unroll
        for (int c = 0; c < CHAINS; c++) {
            if (e[c] >= 0) {
                s[c]  = src[e[c]];
                nx[c] = nxt[e[c]];
            }
        }
        // phase 2: gather feat rows + accumulate; advance chains
        #pragma unroll
        for (int c = 0; c < CHAINS; c++) {
            if (e[c] >= 0) {
                float nl  = norm_l[s[c]];
                float4 v  = ((const float4*)(feat + (size_t)s[c] * D_FEAT))[lane];
                acc[c].x += v.x * nl;
                acc[c].y += v.y * nl;
                acc[c].z += v.z * nl;
                acc[c].w += v.w * nl;
                cnt[c]++;
                e[c] = nx[c];
            }
        }
    }

    #pragma unroll
    for (int c = 0; c < CHAINS; c++) {
        int node = nbase + c;
        if (node < n_nodes) {
            int d = cnt[c] < 1 ? 1 : cnt[c];
            float nr = rsqrtf((float)d);
            float4 a = acc[c];
            a.x *= nr; a.y *= nr; a.z *= nr; a.w *= nr;
            ((float4*)(out + (size_t)node * D_FEAT))[lane] = a;
        }
    }
}

extern "C" void kernel_launch(void* const* d_in, const int* in_sizes, int n_in,
                              void* d_out, int out_size, void* d_ws, size_t ws_size,
                              hipStream_t stream) {
    const float* feat = (const float*)d_in[0];
    const int*   src  = (const int*)d_in[1];
    const int*   dst  = (const int*)d_in[2];
    float* out = (float*)d_out;

    const int n_nodes = in_sizes[0] / D_FEAT;   // 100000
    const int n_edges = in_sizes[1];            // 1600000

    // ws layout (ints): deg_o/norm_l [n_nodes] | head [n_nodes] | nxt [n_edges]
    int* deg_o = (int*)d_ws;
    int* head  = deg_o + n_nodes;
    int* nxt   = head + n_nodes;

    // init: deg_o = 0, head = -1 (0xFF bytes)
    hipMemsetAsync(deg_o, 0x00, (size_t)n_nodes * sizeof(int), stream);
    hipMemsetAsync(head, 0xFF, (size_t)n_nodes * sizeof(int), stream);

    // 1. build out-degrees + dst-linked lists (one pass, coalesced nxt store)
    build_kernel<<<(n_edges + 255) / 256, 256, 0, stream>>>(src, dst, deg_o, head, nxt, n_edges);

    // 2. out-degrees -> rsqrt norms (in place)
    norm_kernel<<<(n_nodes + 255) / 256, 256, 0, stream>>>(deg_o, n_nodes);

    // 3. pull aggregation over chains (no float atomics, fused norm_r)
    {
        int groups = (n_nodes + CHAINS - 1) / CHAINS;
        long long total = (long long)groups * 32;
        int blocks = (int)((total + 255) / 256);
        pull_kernel<<<blocks, 256, 0, stream>>>(feat, src, nxt, head,
                                                (const float*)deg_o, out, n_nodes);
    }
}

// Round 5
// 364.689 us; speedup vs baseline: 1.2815x; 1.1347x over previous
//
#include <hip/hip_runtime.h>
#include <hip/hip_fp16.h>

#define D_FEAT  128
#define CHAINS  8
#define HSLICES 64
#define HBINS   16000   // bins per histogram pass, LDS = 64000 B

// --- 1. build per-dst linked lists: 4 edges/thread, 1 atomic/edge ---
// rec[e] = (src[e], previous edge with same dst). Stores are coalesced int4.
__global__ void build_kernel(const int* __restrict__ src, const int* __restrict__ dst,
                             int* __restrict__ head, int2* __restrict__ rec, int n_edges) {
    int t = blockIdx.x * blockDim.x + threadIdx.x;
    int e = t * 4;
    if (e + 3 < n_edges) {
        int4 s4 = *(const int4*)(src + e);
        int4 d4 = *(const int4*)(dst + e);
        int p0 = atomicExch(&head[d4.x], e + 0);
        int p1 = atomicExch(&head[d4.y], e + 1);
        int p2 = atomicExch(&head[d4.z], e + 2);
        int p3 = atomicExch(&head[d4.w], e + 3);
        int4* r4 = (int4*)(rec + e);
        r4[0] = make_int4(s4.x, p0, s4.y, p1);
        r4[1] = make_int4(s4.z, p2, s4.w, p3);
    } else {
        for (int i = e; i < n_edges; i++) {
            int p = atomicExch(&head[dst[i]], i);
            rec[i] = make_int2(src[i], p);
        }
    }
}

// --- 2a. out-degree histogram, LDS-privatized (no global atomics) ---
// block (s, r): edge slice s, node range r. part[s][bin] written coalesced.
__global__ void hist_kernel(const int* __restrict__ src, int* __restrict__ part,
                            int n_edges, int n_nodes, int slice_len) {
    __shared__ int bins[HBINS];
    int s = blockIdx.x % HSLICES;
    int r = blockIdx.x / HSLICES;
    int lo = r * HBINS;
    int nb = n_nodes - lo; if (nb > HBINS) nb = HBINS;
    for (int i = threadIdx.x; i < nb; i += blockDim.x) bins[i] = 0;
    __syncthreads();
    int beg = s * slice_len;
    int end = beg + slice_len; if (end > n_edges) end = n_edges;
    for (int i = beg + threadIdx.x; i < end; i += blockDim.x) {
        unsigned int u = (unsigned int)(src[i] - lo);
        if (u < (unsigned int)nb) atomicAdd(&bins[u], 1);
    }
    __syncthreads();
    int* dp = part + (size_t)s * n_nodes + lo;
    for (int i = threadIdx.x; i < nb; i += blockDim.x) dp[i] = bins[i];
}

// --- 2b. merge partials -> norm_l = rsqrt(max(deg_o,1)) ---
__global__ void merge_kernel(const int* __restrict__ part, float* __restrict__ norm_l,
                             int n_nodes) {
    int i = blockIdx.x * blockDim.x + threadIdx.x;
    if (i >= n_nodes) return;
    int sum = 0;
    #pragma unroll 8
    for (int s = 0; s < HSLICES; s++) sum += part[(size_t)s * n_nodes + i];
    if (sum < 1) sum = 1;
    norm_l[i] = rsqrtf((float)sum);
}

// --- 3. convert: feat16 = (half)(feat * norm_l[row]); 8 elems/thread ---
__global__ void convert_kernel(const float* __restrict__ feat, const float* __restrict__ norm_l,
                               __half* __restrict__ feat16, int n_nodes) {
    int t = blockIdx.x * blockDim.x + threadIdx.x;
    int total = n_nodes * (D_FEAT / 8);
    if (t >= total) return;
    float nl = norm_l[t >> 4];   // 16 threads per 128-elem row
    const float4* fp = (const float4*)feat + (size_t)t * 2;
    float4 a = fp[0], b = fp[1];
    __half2 h0 = __floats2half2_rn(a.x * nl, a.y * nl);
    __half2 h1 = __floats2half2_rn(a.z * nl, a.w * nl);
    __half2 h2 = __floats2half2_rn(b.x * nl, b.y * nl);
    __half2 h3 = __floats2half2_rn(b.z * nl, b.w * nl);
    uint4 o;
    o.x = *(unsigned int*)&h0; o.y = *(unsigned int*)&h1;
    o.z = *(unsigned int*)&h2; o.w = *(unsigned int*)&h3;
    ((uint4*)feat16)[t] = o;
}

// --- 4. pull: 32 lanes per node, 8 interleaved chains, fp16 pre-scaled rows ---
__global__ __launch_bounds__(256) void pull_kernel(
        const __half* __restrict__ feat16, const int2* __restrict__ rec,
        const int* __restrict__ head, float* __restrict__ out, int n_nodes) {
    long long gid = (long long)blockIdx.x * blockDim.x + threadIdx.x;
    int group = (int)(gid >> 5);
    int lane  = (int)(gid & 31);
    int nbase = group * CHAINS;
    if (nbase >= n_nodes) return;

    int    e[CHAINS];
    int    cnt[CHAINS];
    float4 acc[CHAINS];
    #pragma unroll
    for (int c = 0; c < CHAINS; c++) {
        int node = nbase + c;
        e[c] = (node < n_nodes) ? head[node] : -1;
        cnt[c] = 0;
        acc[c] = make_float4(0.f, 0.f, 0.f, 0.f);
    }

    for (;;) {
        bool any = false;
        #pragma unroll
        for (int c = 0; c < CHAINS; c++) any = any || (e[c] >= 0);
        if (!any) break;
        int2 rc[CHAINS];
        #pragma unroll
        for (int c = 0; c < CHAINS; c++)
            if (e[c] >= 0) rc[c] = rec[e[c]];
        #pragma unroll
        for (int c = 0; c < CHAINS; c++) {
            if (e[c] >= 0) {
                uint2 hv = ((const uint2*)(feat16 + (size_t)rc[c].x * D_FEAT))[lane];
                float2 f0 = __half22float2(*(__half2*)&hv.x);
                float2 f1 = __half22float2(*(__half2*)&hv.y);
                acc[c].x += f0.x; acc[c].y += f0.y;
                acc[c].z += f1.x; acc[c].w += f1.y;
                cnt[c]++;
                e[c] = rc[c].y;
            }
        }
    }

    #pragma unroll
    for (int c = 0; c < CHAINS; c++) {
        int node = nbase + c;
        if (node < n_nodes) {
            int d = cnt[c] < 1 ? 1 : cnt[c];
            float nr = rsqrtf((float)d);
            float4 a = acc[c];
            a.x *= nr; a.y *= nr; a.z *= nr; a.w *= nr;
            ((float4*)(out + (size_t)node * D_FEAT))[lane] = a;
        }
    }
}

// --- fallback pull reading fp32 feat directly (if ws too small for feat16) ---
__global__ __launch_bounds__(256) void pull_f32_kernel(
        const float* __restrict__ feat, const int2* __restrict__ rec,
        const int* __restrict__ head, const float* __restrict__ norm_l,
        float* __restrict__ out, int n_nodes) {
    long long gid = (long long)blockIdx.x * blockDim.x + threadIdx.x;
    int group = (int)(gid >> 5);
    int lane  = (int)(gid & 31);
    int nbase = group * CHAINS;
    if (nbase >= n_nodes) return;
    int e[CHAINS]; int cnt[CHAINS]; float4 acc[CHAINS];
    #pragma unroll
    for (int c = 0; c < CHAINS; c++) {
        int node = nbase + c;
        e[c] = (node < n_nodes) ? head[node] : -1;
        cnt[c] = 0;
        acc[c] = make_float4(0.f, 0.f, 0.f, 0.f);
    }
    for (;;) {
        bool any = false;
        #pragma unroll
        for (int c = 0; c < CHAINS; c++) any = any || (e[c] >= 0);
        if (!any) break;
        int2 rc[CHAINS];
        #pragma unroll
        for (int c = 0; c < CHAINS; c++)
            if (e[c] >= 0) rc[c] = rec[e[c]];
        #pragma unroll
        for (int c = 0; c < CHAINS; c++) {
            if (e[c] >= 0) {
                float nl = norm_l[rc[c].x];
                float4 v = ((const float4*)(feat + (size_t)rc[c].x * D_FEAT))[lane];
                acc[c].x += v.x * nl; acc[c].y += v.y * nl;
                acc[c].z += v.z * nl; acc[c].w += v.w * nl;
                cnt[c]++;
                e[c] = rc[c].y;
            }
        }
    }
    #pragma unroll
    for (int c = 0; c < CHAINS; c++) {
        int node = nbase + c;
        if (node < n_nodes) {
            int d = cnt[c] < 1 ? 1 : cnt[c];
            float nr = rsqrtf((float)d);
            float4 a = acc[c];
            a.x *= nr; a.y *= nr; a.z *= nr; a.w *= nr;
            ((float4*)(out + (size_t)node * D_FEAT))[lane] = a;
        }
    }
}

extern "C" void kernel_launch(void* const* d_in, const int* in_sizes, int n_in,
                              void* d_out, int out_size, void* d_ws, size_t ws_size,
                              hipStream_t stream) {
    const float* feat = (const float*)d_in[0];
    const int*   src  = (const int*)d_in[1];
    const int*   dst  = (const int*)d_in[2];
    float* out = (float*)d_out;

    const int n_nodes = in_sizes[0] / D_FEAT;   // 100000
    const int n_edges = in_sizes[1];            // 1600000
    const int NR = (n_nodes + HBINS - 1) / HBINS;         // 7 ranges
    const int slice_len = (n_edges + HSLICES - 1) / HSLICES;

    // ws layout: head[n] | rec[2*n_edges] | norm_l[n] | union{ part[64*n] , feat16[n*128 halfs] }
    int*   head   = (int*)d_ws;
    int2*  rec    = (int2*)(head + n_nodes);
    float* norm_l = (float*)(rec + n_edges);
    int*   part   = (int*)(norm_l + n_nodes);
    __half* feat16 = (__half*)part;   // reuses part's space after merge

    size_t fixed  = (size_t)n_nodes * 4 + (size_t)n_edges * 8 + (size_t)n_nodes * 4;
    size_t big    = (size_t)HSLICES * n_nodes * 4;                    // part: 25.6 MB
    size_t f16sz  = (size_t)n_nodes * D_FEAT * 2;                     // feat16: 25.6 MB
    bool use_f16  = ws_size >= fixed + (big > f16sz ? big : f16sz);

    // init heads to -1
    hipMemsetAsync(head, 0xFF, (size_t)n_nodes * sizeof(int), stream);

    // 1. build chains
    {
        int nthreads = (n_edges + 3) / 4;
        build_kernel<<<(nthreads + 255) / 256, 256, 0, stream>>>(src, dst, head, rec, n_edges);
    }

    if (use_f16) {
        // 2. out-degree histogram + merge -> norm_l
        hist_kernel<<<HSLICES * NR, 256, 0, stream>>>(src, part, n_edges, n_nodes, slice_len);
        merge_kernel<<<(n_nodes + 255) / 256, 256, 0, stream>>>(part, norm_l, n_nodes);
        // 3. fp16 pre-scaled features (overwrites part)
        {
            int total = n_nodes * (D_FEAT / 8);
            convert_kernel<<<(total + 255) / 256, 256, 0, stream>>>(feat, norm_l, feat16, n_nodes);
        }
        // 4. pull
        {
            int groups = (n_nodes + CHAINS - 1) / CHAINS;
            long long total = (long long)groups * 32;
            pull_kernel<<<(int)((total + 255) / 256), 256, 0, stream>>>(feat16, rec, head,
                                                                        out, n_nodes);
        }
    } else {
        // fallback: histogram + fp32 pull (no feat16 buffer)
        hist_kernel<<<HSLICES * NR, 256, 0, stream>>>(src, part, n_edges, n_nodes, slice_len);
        merge_kernel<<<(n_nodes + 255) / 256, 256, 0, stream>>>(part, norm_l, n_nodes);
        int groups = (n_nodes + CHAINS - 1) / CHAINS;
        long long total = (long long)groups * 32;
        pull_f32_kernel<<<(int)((total + 255) / 256), 256, 0, stream>>>(feat, rec, head,
                                                                        norm_l, out, n_nodes);
    }
}